// Round 1
// 115.086 us; speedup vs baseline: 1.0437x; 1.0437x over previous
//
#include <hip/hip_runtime.h>
#include <hip/hip_bf16.h>

typedef _Float16 half8 __attribute__((ext_vector_type(8)));
typedef _Float16 half4v __attribute__((ext_vector_type(4)));
typedef float floatx4 __attribute__((ext_vector_type(4)));
typedef unsigned int uint2v __attribute__((ext_vector_type(2)));

// 100^(i/8), i=0..7, correctly rounded
__device__ const float FREQS[8] = {
    1.0f, 1.7782794100389228f, 3.1622776601683795f, 5.623413251903491f,
    10.0f, 17.78279410038923f, 31.622776601683793f, 56.23413251903491f};

// sin/cos of m (radians) via 2-term Cody-Waite reduction into revolutions,
// then v_sin_f32/v_cos_f32. Error ~|m|*2^-48, far below f16 rounding.
__device__ inline void fsincos(float m, float& s, float& c) {
  constexpr double I2PI_D = 0.15915494309189533576888376337251;
  constexpr float HI = (float)I2PI_D;
  constexpr float LO = (float)(I2PI_D - (double)HI);
  float k = rintf(m * HI);
  float f = fmaf(m, HI, -k);
  f = fmaf(m, LO, f);
  s = __builtin_amdgcn_sinf(f);
  c = __builtin_amdgcn_cosf(f);
}

// fast silu: v_exp + v_rcp (~1ulp), avoids the precise-division sequence
__device__ inline float fsilu(float x) {
  return x * __builtin_amdgcn_rcpf(1.f + __expf(-x));
}

// ---------------- kernel 0: weight prep ----------------
// W1t/W2t: [n][k] f16. W3f: MFMA-fragment-major so layer3's weight loads are
// coalesced 16B/lane: element (n,k) -> [(n>>4)*8 + k>>5][lane=((k>>3)&3)*16 + (n&15)][k&7]
__global__ __launch_bounds__(256) void prep_weights(
    const float* __restrict__ W1, const float* __restrict__ W2,
    const float* __restrict__ W3, _Float16* __restrict__ W1t,
    _Float16* __restrict__ W2t, _Float16* __restrict__ W3f) {
  int tid = blockIdx.x * blockDim.x + threadIdx.x;
  int stride = gridDim.x * blockDim.x;
  for (int i = tid; i < 128 * 32; i += stride) {
    int n = i >> 5, k = i & 31;
    W1t[i] = (_Float16)W1[k * 128 + n];
  }
  for (int i = tid; i < 256 * 128; i += stride) {
    int n = i >> 7, k = i & 127;
    W2t[i] = (_Float16)W2[k * 256 + n];
  }
  for (int i = tid; i < 512 * 256; i += stride) {  // coalesced read of W3
    int k = i >> 9, n = i & 511;
    int it = n >> 4, ln = n & 15, ks = k >> 5, q = (k >> 3) & 3, j = k & 7;
    W3f[((size_t)(it * 8 + ks) * 64 + q * 16 + ln) * 8 + j] = (_Float16)W3[i];
  }
}

// ---------------- kernel 1: feats + L1 + L2 + one-hot MFMA scatter ----------------
// 512 blocks = (bv[6]|tsel[1]|pg[2]), 512 threads (8 waves), 256 pts as 2x128 chunks.
// Wave w: L1 for its 16 pts/chunk (h1^T via swapped MFMA -> packed LDS), then
// L2 + scatter for 32 cols [32w,32w+32). Scatter via mfma_16x16x16f16 one-hot A.
// NEW vs prior round: the one-hot A matrix is materialized ONCE per chunk in LDS
// (oneh[64 cells][128 pts], 136-half row stride -> conflict-free ds_read_b64)
// by the 128 point-owner threads, instead of every wave rebuilding it with
// ~48 cmp/cndmask/or VALU ops per mt. Also the L2 inner loop is restructured
// (cc0/cc1 one-pass, hb0/hb1 hoisted, ao read feeds 2 MFMAs) and unrolling is
// capped so peak VGPR demand stays under the 128-reg cap of (512,4) -> no spills.
#define HS 136
#define OHS 136
__global__ __launch_bounds__(512, 4) void embed_scatter(
    const float* __restrict__ dstart, const float* __restrict__ dend,
    const float* __restrict__ b1, const float* __restrict__ b2,
    const _Float16* __restrict__ W1t, const _Float16* __restrict__ W2t,
    _Float16* __restrict__ swz, int* __restrict__ counts) {
  __shared__ __align__(16) _Float16 h1t[128 * HS];   // 34816 B
  __shared__ __align__(16) _Float16 oneh[64 * OHS];  // 17408 B one-hot [cell][pt]
  __shared__ __align__(16) _Float16 W1lds[4096];     // 8192 B
  __shared__ float b1lds[128];
  __shared__ int hist[64];
  // total LDS = 61184 B -> 2 blocks/CU preserved

  int bid = blockIdx.x;
  int bv = bid >> 3, tsel = (bid >> 2) & 1, pg = bid & 3;
  const float* src = tsel ? dend : dstart;
  int tid = threadIdx.x;
  int lane = tid & 63, w = tid >> 6, ln = lane & 15, q = lane >> 4;

  *(half8*)&W1lds[tid * 8] = *(const half8*)&W1t[tid * 8];
  if (tid < 128) b1lds[tid] = b1[tid];
  if (tid < 64) hist[tid] = 0;
  {  // zero one-hot for chunk 0 (joins the staging phase before first barrier)
    half8 zz = {};
    for (int i = tid; i < (64 * OHS) / 8; i += 512) ((half8*)oneh)[i] = zz;
  }

  half8 w2f[2][4];  // B-frag of W2: n=32w+16nt+ln, k=32ks+8q+j
  float b2v[2];
  for (int nt = 0; nt < 2; nt++) {
    int n = w * 32 + nt * 16 + ln;
    b2v[nt] = b2[n];
    for (int ks = 0; ks < 4; ks++)
      w2f[nt][ks] = *(const half8*)&W2t[n * 128 + ks * 32 + q * 8];
  }
  floatx4 sacc[4][2];  // cell=16mc+4q+r, col=32w+16nt+ln
  for (int mc = 0; mc < 4; mc++)
    for (int nt = 0; nt < 2; nt++) sacc[mc][nt] = (floatx4){0.f, 0.f, 0.f, 0.f};

  float fA = FREQS[2 * q], fB = FREQS[2 * q + 1];
  int pbase = bv * 1024 + pg * 256;
  __syncthreads();

  for (int c = 0; c < 2; c++) {
    if (c) {  // re-zero one-hot for chunk 1; extra barrier separates from setters
      half8 zz = {};
      for (int i = tid; i < (64 * OHS) / 8; i += 512) ((half8*)oneh)[i] = zz;
      __syncthreads();
    }
    int pl = c * 128 + w * 16 + ln;
    float2 xy = *(const float2*)&src[(size_t)(pbase + pl) * 2];
    if (q == 0) {
      int cell = ((int)xy.x >> 6) * 8 + ((int)xy.y >> 6);
      atomicAdd(&hist[cell], 1);
      oneh[cell * OHS + w * 16 + ln] = (_Float16)1.0f;  // one-hot set
    }
    half8 fb;  // feats B-frag: n=pt=ln, k=8q+j -> freqs 2q,2q+1
    {
      float s, cc2;
      fsincos(xy.x * fA, s, cc2); fb[0] = (_Float16)s; fb[2] = (_Float16)cc2;
      fsincos(xy.y * fA, s, cc2); fb[1] = (_Float16)s; fb[3] = (_Float16)cc2;
      fsincos(xy.x * fB, s, cc2); fb[4] = (_Float16)s; fb[6] = (_Float16)cc2;
      fsincos(xy.y * fB, s, cc2); fb[5] = (_Float16)s; fb[7] = (_Float16)cc2;
    }
    // L1 swapped: C[m=h1col][n=pt]; silu -> packed b64 LDS write
#pragma unroll 2
    for (int mtW = 0; mtW < 8; mtW++) {
      half8 w1f = *(const half8*)&W1lds[(mtW * 16 + ln) * 32 + q * 8];
      floatx4 c1 = *(const floatx4*)&b1lds[mtW * 16 + q * 4];
      c1 = __builtin_amdgcn_mfma_f32_16x16x32_f16(w1f, fb, c1, 0, 0, 0);
      half4v hv;
      for (int r = 0; r < 4; r++) hv[r] = (_Float16)fsilu(c1[r]);
      *(half4v*)&h1t[(w * 16 + ln) * HS + mtW * 16 + q * 4] = hv;
    }
    __syncthreads();
    // L2 + one-hot scatter; unroll 1 keeps peak VGPR demand < 128 (no spills)
#pragma unroll 1
    for (int mt = 0; mt < 8; mt++) {
      half8 af[4];
      for (int ks = 0; ks < 4; ks++)
        af[ks] = *(const half8*)&h1t[(mt * 16 + ln) * HS + ks * 32 + q * 8];
      floatx4 cc0 = {b2v[0], b2v[0], b2v[0], b2v[0]};
      floatx4 cc1 = {b2v[1], b2v[1], b2v[1], b2v[1]};
      for (int ks = 0; ks < 4; ks++) {
        cc0 = __builtin_amdgcn_mfma_f32_16x16x32_f16(af[ks], w2f[0][ks], cc0, 0, 0, 0);
        cc1 = __builtin_amdgcn_mfma_f32_16x16x32_f16(af[ks], w2f[1][ks], cc1, 0, 0, 0);
      }
      half4v hb0, hb1;  // C-layout == scatter B-layout (k=pt=4q+r, n=col=ln)
      for (int r = 0; r < 4; r++) {
        hb0[r] = (_Float16)fsilu(cc0[r]);
        hb1[r] = (_Float16)fsilu(cc1[r]);
      }
      for (int mc = 0; mc < 4; mc++) {
        // one-hot A-frag: m=16mc+ln (cell), k=4q+j (pt) -- conflict-free b64
        half4v ao = *(const half4v*)&oneh[(mc * 16 + ln) * OHS + mt * 16 + q * 4];
        sacc[mc][0] = __builtin_amdgcn_mfma_f32_16x16x16f16(ao, hb0, sacc[mc][0], 0, 0, 0);
        sacc[mc][1] = __builtin_amdgcn_mfma_f32_16x16x16f16(ao, hb1, sacc[mc][1], 0, 0, 0);
      }
    }
    __syncthreads();
  }
  // coalesced swizzled store: element (bid, mc, wnt=2w+nt, lane) = half4 (r0..r3)
  for (int mc = 0; mc < 4; mc++)
    for (int nt = 0; nt < 2; nt++) {
      half4v hv;
      for (int r = 0; r < 4; r++) hv[r] = (_Float16)sacc[mc][nt][r];
      *(half4v*)&swz[((((size_t)bid * 4 + mc) * 16 + w * 2 + nt) * 64 + lane) * 4] = hv;
    }
  if (tid < 64) counts[bid * 64 + tid] = hist[tid];
}

// ---------------- kernel 2: out = (Σ_pg partial) @ W3 + count*b3 ----------------
// 512 blocks = (bvts[128], cellquarter[4]): 16 cells x 512 cols. Unswizzle 4 pg
// partials into a 16x256 f16 LDS tile; swapped GEMM (A=W3 frags, B=cells) so
// stores are cell-contiguous 64B lines.
#define AS 264
__global__ __launch_bounds__(256) void layer3(
    const _Float16* __restrict__ swz, const int* __restrict__ counts,
    const _Float16* __restrict__ W3f, const float* __restrict__ b3,
    float* __restrict__ out) {
  __shared__ _Float16 a_lds[16 * AS];
  __shared__ float cnt_s[16];
  int bb = blockIdx.x;
  int bvts = bb >> 2, cq = bb & 3;
  int tid = threadIdx.x;
  for (int it = 0; it < 4; it++) {
    int cc = it * 256 + tid;
    int wn = cc >> 6, lane2 = cc & 63, q2 = lane2 >> 4, ln2 = lane2 & 15;
    size_t base = ((size_t)bvts * 16 + cq) * 1024 + cc;
    half4v s = (*(const half4v*)&swz[base * 4] +
                *(const half4v*)&swz[(base + 4096) * 4]) +
               (*(const half4v*)&swz[(base + 8192) * 4] +
                *(const half4v*)&swz[(base + 12288) * 4]);
    int col = wn * 16 + ln2;
    for (int r = 0; r < 4; r++) a_lds[(q2 * 4 + r) * AS + col] = s[r];
  }
  if (tid < 16) {
    int base = bvts * 4 * 64 + cq * 16 + tid;
    cnt_s[tid] = (float)(counts[base] + counts[base + 64] +
                         counts[base + 128] + counts[base + 192]);
  }
  __syncthreads();
  int lane = tid & 63, w = tid >> 6, ln = lane & 15, q = lane >> 4;
  half8 af[8];  // B-frag: n=cell=ln, k=32ks+8q+j (col)
  for (int ks = 0; ks < 8; ks++)
    af[ks] = *(const half8*)&a_lds[ln * AS + ks * 32 + q * 8];
  float cntf = cnt_s[ln];
  for (int ii = 0; ii < 8; ii++) {
    int i = w * 8 + ii;  // 16-col tile of 512
    half8 wf[8];
    for (int ks = 0; ks < 8; ks++)
      wf[ks] = *(const half8*)&W3f[((size_t)(i * 8 + ks) * 64 + lane) * 8];
    floatx4 b3v = *(const floatx4*)&b3[i * 16 + q * 4];
    floatx4 acc = {0.f, 0.f, 0.f, 0.f};
    for (int ks = 0; ks < 8; ks++)
      acc = __builtin_amdgcn_mfma_f32_16x16x32_f16(wf[ks], af[ks], acc, 0, 0, 0);
    for (int r = 0; r < 4; r++)
      out[((size_t)bvts * 512 + i * 16 + q * 4 + r) * 64 + cq * 16 + ln] =
          acc[r] + cntf * b3v[r];
  }
}

extern "C" void kernel_launch(void* const* d_in, const int* in_sizes, int n_in,
                              void* d_out, int out_size, void* d_ws, size_t ws_size,
                              hipStream_t stream) {
  const float* dstart = (const float*)d_in[0];
  const float* dend = (const float*)d_in[1];
  const float* W1 = (const float*)d_in[2];
  const float* b1 = (const float*)d_in[3];
  const float* W2 = (const float*)d_in[4];
  const float* b2 = (const float*)d_in[5];
  const float* W3 = (const float*)d_in[6];
  const float* b3 = (const float*)d_in[7];
  float* out = (float*)d_out;

  char* ws = (char*)d_ws;
  _Float16* W1t = (_Float16*)(ws);                  // 8 KB
  _Float16* W2t = (_Float16*)(ws + 8192);           // 64 KB
  _Float16* W3f = (_Float16*)(ws + 73728);          // 256 KB
  _Float16* swz = (_Float16*)(ws + 335872);         // 512*64*256*2 = 16 MB
  int* counts = (int*)(ws + 335872 + 16777216);     // 128 KB

  hipLaunchKernelGGL(prep_weights, dim3(64), dim3(256), 0, stream,
                     W1, W2, W3, W1t, W2t, W3f);
  hipLaunchKernelGGL(embed_scatter, dim3(512), dim3(512), 0, stream,
                     dstart, dend, b1, b2, W1t, W2t, swz, counts);
  hipLaunchKernelGGL(layer3, dim3(512), dim3(256), 0, stream,
                     swz, counts, W3f, b3, out);
}

// Round 2
// 111.490 us; speedup vs baseline: 1.0774x; 1.0323x over previous
//
#include <hip/hip_runtime.h>
#include <hip/hip_bf16.h>

typedef _Float16 half8 __attribute__((ext_vector_type(8)));
typedef _Float16 half4v __attribute__((ext_vector_type(4)));
typedef float floatx4 __attribute__((ext_vector_type(4)));
typedef float float4v __attribute__((ext_vector_type(4)));

// 100^(i/8), i=0..7, correctly rounded
__device__ const float FREQS[8] = {
    1.0f, 1.7782794100389228f, 3.1622776601683795f, 5.623413251903491f,
    10.0f, 17.78279410038923f, 31.622776601683793f, 56.23413251903491f};

// sin/cos of m (radians) via 2-term Cody-Waite reduction into revolutions,
// then v_sin_f32/v_cos_f32. Error ~|m|*2^-48, far below f16 rounding.
__device__ inline void fsincos(float m, float& s, float& c) {
  constexpr double I2PI_D = 0.15915494309189533576888376337251;
  constexpr float HI = (float)I2PI_D;
  constexpr float LO = (float)(I2PI_D - (double)HI);
  float k = rintf(m * HI);
  float f = fmaf(m, HI, -k);
  f = fmaf(m, LO, f);
  s = __builtin_amdgcn_sinf(f);
  c = __builtin_amdgcn_cosf(f);
}

// fast silu: v_exp + v_rcp (~1ulp), avoids the precise-division sequence
__device__ inline float fsilu(float x) {
  return x * __builtin_amdgcn_rcpf(1.f + __expf(-x));
}

// ---------------- kernel 0: W3 -> MFMA-fragment-major f16 ----------------
// One half8 fragment per thread: 16384 threads, coalesced 16B stores.
// W3f element (n,k) -> frag f=((n>>4)*8 + k>>5)*64 + ((k>>3)&3)*16 + (n&15), j=k&7
__global__ __launch_bounds__(256) void prep_w3(
    const float* __restrict__ W3, _Float16* __restrict__ W3f) {
  int f = blockIdx.x * 256 + threadIdx.x;  // 0..16383
  int ln = f & 15, q = (f >> 4) & 3, ks = (f >> 6) & 7, it = f >> 9;
  int n = it * 16 + ln;
  half8 t;
  for (int j = 0; j < 8; j++)
    t[j] = (_Float16)W3[(size_t)(ks * 32 + q * 8 + j) * 512 + n];
  *(half8*)&W3f[(size_t)f * 8] = t;
}

// ---------------- kernel 1: feats + L1 + L2 + one-hot MFMA scatter ----------------
// 512 blocks = (bv[6]|tsel[1]|pg[2]), 512 threads (8 waves), 256 pts as 2x128 chunks.
// Wave w: L1 for its 16 pts/chunk (h1^T via swapped MFMA -> packed LDS), then
// L2 + scatter for 32 cols [32w,32w+32). Scatter via mfma_16x16x16f16 one-hot A
// materialized in LDS (oneh[cell][pt]) by the 128 point-owner threads.
// NEW vs prior round: W1/W2 converted f32->f16 inline (prep dependency removed);
// chunk-1 oneh re-zero loop + barrier replaced by incremental clear (each setter
// zeroes its previous (cell,pt) slot; pt column is thread-private, and the
// loop-end / post-L1 barriers already fence all readers).
#define HS 136
#define OHS 136
__global__ __launch_bounds__(512, 4) void embed_scatter(
    const float* __restrict__ dstart, const float* __restrict__ dend,
    const float* __restrict__ W1, const float* __restrict__ b1,
    const float* __restrict__ W2, const float* __restrict__ b2,
    _Float16* __restrict__ swz, int* __restrict__ counts) {
  __shared__ __align__(16) _Float16 h1t[128 * HS];   // 34816 B
  __shared__ __align__(16) _Float16 oneh[64 * OHS];  // 17408 B one-hot [cell][pt]
  __shared__ __align__(16) _Float16 W1lds[4096];     // 8192 B
  __shared__ float b1lds[128];
  __shared__ int hist[64];

  int bid = blockIdx.x;
  int bv = bid >> 3, tsel = (bid >> 2) & 1, pg = bid & 3;
  const float* src = tsel ? dend : dstart;
  int tid = threadIdx.x;
  int lane = tid & 63, w = tid >> 6, ln = lane & 15, q = lane >> 4;

  // stage W1 (f32 [32][128] row-major) -> W1lds[n*32+k] f16, coalesced reads
  {
    float4v v0 = *(const float4v*)&W1[tid * 8];
    float4v v1 = *(const float4v*)&W1[tid * 8 + 4];
    for (int e = 0; e < 8; e++) {
      int idx = tid * 8 + e;
      int k = idx >> 7, n = idx & 127;
      W1lds[n * 32 + k] = (_Float16)(e < 4 ? v0[e] : v1[e - 4]);
    }
  }
  if (tid < 128) b1lds[tid] = b1[tid];
  if (tid < 64) hist[tid] = 0;
  {  // zero one-hot for chunk 0
    half8 zz = {};
    for (int i = tid; i < (64 * OHS) / 8; i += 512) ((half8*)oneh)[i] = zz;
  }

  // B-frag of W2 (f32 [128][256] row-major): n=32w+16nt+ln, k=32ks+8q+j
  half8 w2f[2][4];
  float b2v[2];
  for (int nt = 0; nt < 2; nt++) {
    int n = w * 32 + nt * 16 + ln;
    b2v[nt] = b2[n];
    for (int ks = 0; ks < 4; ks++) {
      half8 t;
      for (int j = 0; j < 8; j++)
        t[j] = (_Float16)W2[(size_t)(ks * 32 + q * 8 + j) * 256 + n];
      w2f[nt][ks] = t;
    }
  }
  floatx4 sacc[4][2];  // cell=16mc+4q+r, col=32w+16nt+ln
  for (int mc = 0; mc < 4; mc++)
    for (int nt = 0; nt < 2; nt++) sacc[mc][nt] = (floatx4){0.f, 0.f, 0.f, 0.f};

  float fA = FREQS[2 * q], fB = FREQS[2 * q + 1];
  int pbase = bv * 1024 + pg * 256;
  int prevcell = 0;
  __syncthreads();

  for (int c = 0; c < 2; c++) {
    int pl = c * 128 + w * 16 + ln;
    float2 xy = *(const float2*)&src[(size_t)(pbase + pl) * 2];
    if (q == 0) {
      int cell = ((int)xy.x >> 6) * 8 + ((int)xy.y >> 6);
      if (c) oneh[prevcell * OHS + w * 16 + ln] = (_Float16)0.0f;  // clear old
      prevcell = cell;
      atomicAdd(&hist[cell], 1);
      oneh[cell * OHS + w * 16 + ln] = (_Float16)1.0f;  // set new
    }
    half8 fb;  // feats B-frag: n=pt=ln, k=8q+j -> freqs 2q,2q+1
    {
      float s, cc2;
      fsincos(xy.x * fA, s, cc2); fb[0] = (_Float16)s; fb[2] = (_Float16)cc2;
      fsincos(xy.y * fA, s, cc2); fb[1] = (_Float16)s; fb[3] = (_Float16)cc2;
      fsincos(xy.x * fB, s, cc2); fb[4] = (_Float16)s; fb[6] = (_Float16)cc2;
      fsincos(xy.y * fB, s, cc2); fb[5] = (_Float16)s; fb[7] = (_Float16)cc2;
    }
    // L1 swapped: C[m=h1col][n=pt]; silu -> packed b64 LDS write
#pragma unroll 2
    for (int mtW = 0; mtW < 8; mtW++) {
      half8 w1f = *(const half8*)&W1lds[(mtW * 16 + ln) * 32 + q * 8];
      floatx4 c1 = *(const floatx4*)&b1lds[mtW * 16 + q * 4];
      c1 = __builtin_amdgcn_mfma_f32_16x16x32_f16(w1f, fb, c1, 0, 0, 0);
      half4v hv;
      for (int r = 0; r < 4; r++) hv[r] = (_Float16)fsilu(c1[r]);
      *(half4v*)&h1t[(w * 16 + ln) * HS + mtW * 16 + q * 4] = hv;
    }
    __syncthreads();
    // L2 + one-hot scatter; unroll 1 keeps peak VGPR demand < 128 (no spills)
#pragma unroll 1
    for (int mt = 0; mt < 8; mt++) {
      half8 af[4];
      for (int ks = 0; ks < 4; ks++)
        af[ks] = *(const half8*)&h1t[(mt * 16 + ln) * HS + ks * 32 + q * 8];
      floatx4 cc0 = {b2v[0], b2v[0], b2v[0], b2v[0]};
      floatx4 cc1 = {b2v[1], b2v[1], b2v[1], b2v[1]};
      for (int ks = 0; ks < 4; ks++) {
        cc0 = __builtin_amdgcn_mfma_f32_16x16x32_f16(af[ks], w2f[0][ks], cc0, 0, 0, 0);
        cc1 = __builtin_amdgcn_mfma_f32_16x16x32_f16(af[ks], w2f[1][ks], cc1, 0, 0, 0);
      }
      half4v hb0, hb1;  // C-layout == scatter B-layout (k=pt=4q+r, n=col=ln)
      for (int r = 0; r < 4; r++) {
        hb0[r] = (_Float16)fsilu(cc0[r]);
        hb1[r] = (_Float16)fsilu(cc1[r]);
      }
      for (int mc = 0; mc < 4; mc++) {
        // one-hot A-frag: m=16mc+ln (cell), k=4q+j (pt) -- conflict-free b64
        half4v ao = *(const half4v*)&oneh[(mc * 16 + ln) * OHS + mt * 16 + q * 4];
        sacc[mc][0] = __builtin_amdgcn_mfma_f32_16x16x16f16(ao, hb0, sacc[mc][0], 0, 0, 0);
        sacc[mc][1] = __builtin_amdgcn_mfma_f32_16x16x16f16(ao, hb1, sacc[mc][1], 0, 0, 0);
      }
    }
    __syncthreads();
  }
  // coalesced swizzled store: element (bid, mc, wnt=2w+nt, lane) = half4 (r0..r3)
  for (int mc = 0; mc < 4; mc++)
    for (int nt = 0; nt < 2; nt++) {
      half4v hv;
      for (int r = 0; r < 4; r++) hv[r] = (_Float16)sacc[mc][nt][r];
      *(half4v*)&swz[((((size_t)bid * 4 + mc) * 16 + w * 2 + nt) * 64 + lane) * 4] = hv;
    }
  if (tid < 64) counts[bid * 64 + tid] = hist[tid];
}

// ---------------- kernel 2: out = (Σ_pg partial) @ W3 + count*b3 ----------------
// 256 blocks = (bvts[128], ocol-half[2]): each block owns ALL 64 cells and 256
// output cols. Unswizzles 4 pg partials into a 64x256 f16 LDS tile (full K),
// then swapped GEMM (A=W3 frags m=ocol, B=cells n=ln within 4 cell-tiles).
// i-outer / ct-inner: each W3f fragment is fetched exactly once per block ->
// W3f traffic 128MB -> 32MB vs prior round.
#define AS 264
__global__ __launch_bounds__(256) void layer3(
    const _Float16* __restrict__ swz, const int* __restrict__ counts,
    const _Float16* __restrict__ W3f, const float* __restrict__ b3,
    float* __restrict__ out) {
  __shared__ _Float16 a_lds[64 * AS];  // 33792 B
  __shared__ float cnt_s[64];
  int bb = blockIdx.x;
  int bvts = bb >> 1, oh = bb & 1;
  int tid = threadIdx.x;
  // unswizzle + 4-pg reduce: f in 0..4095 indexes (mc,wnt,lane) half4v groups
  for (int it = 0; it < 16; it++) {
    int f = it * 256 + tid;
    size_t base = ((size_t)bvts * 4) * 4096 + f;
    half4v s = (*(const half4v*)&swz[base * 4] +
                *(const half4v*)&swz[(base + 4096) * 4]) +
               (*(const half4v*)&swz[(base + 8192) * 4] +
                *(const half4v*)&swz[(base + 12288) * 4]);
    int mc = f >> 10, wnt = (f >> 6) & 15, lane2 = f & 63;
    int q2 = lane2 >> 4, ln2 = lane2 & 15;
    int k = wnt * 16 + ln2;
    for (int r = 0; r < 4; r++) a_lds[(mc * 16 + q2 * 4 + r) * AS + k] = s[r];
  }
  if (tid < 64) {
    int base = bvts * 4 * 64 + tid;
    cnt_s[tid] = (float)(counts[base] + counts[base + 64] +
                         counts[base + 128] + counts[base + 192]);
  }
  __syncthreads();
  int lane = tid & 63, w = tid >> 6, ln = lane & 15, q = lane >> 4;
  for (int ii = 0; ii < 4; ii++) {
    int ig = oh * 16 + w * 4 + ii;  // 16-col tile of 512
    half8 wf[8];
    for (int ks = 0; ks < 8; ks++)
      wf[ks] = *(const half8*)&W3f[((size_t)(ig * 8 + ks) * 64 + lane) * 8];
    floatx4 b3v = *(const floatx4*)&b3[ig * 16 + q * 4];
    for (int ct = 0; ct < 4; ct++) {
      half8 af[8];  // B-frag: n=cell=ct*16+ln, k=32ks+8q+j
      for (int ks = 0; ks < 8; ks++)
        af[ks] = *(const half8*)&a_lds[(ct * 16 + ln) * AS + ks * 32 + q * 8];
      floatx4 acc = {0.f, 0.f, 0.f, 0.f};
      for (int ks = 0; ks < 8; ks++)
        acc = __builtin_amdgcn_mfma_f32_16x16x32_f16(wf[ks], af[ks], acc, 0, 0, 0);
      float cntf = cnt_s[ct * 16 + ln];
      for (int r = 0; r < 4; r++)
        out[((size_t)bvts * 512 + ig * 16 + q * 4 + r) * 64 + ct * 16 + ln] =
            acc[r] + cntf * b3v[r];
    }
  }
}

extern "C" void kernel_launch(void* const* d_in, const int* in_sizes, int n_in,
                              void* d_out, int out_size, void* d_ws, size_t ws_size,
                              hipStream_t stream) {
  const float* dstart = (const float*)d_in[0];
  const float* dend = (const float*)d_in[1];
  const float* W1 = (const float*)d_in[2];
  const float* b1 = (const float*)d_in[3];
  const float* W2 = (const float*)d_in[4];
  const float* b2 = (const float*)d_in[5];
  const float* W3 = (const float*)d_in[6];
  const float* b3 = (const float*)d_in[7];
  float* out = (float*)d_out;

  char* ws = (char*)d_ws;
  _Float16* W3f = (_Float16*)(ws);                  // 512*256*2 = 256 KB
  _Float16* swz = (_Float16*)(ws + 262144);         // 512*64*256*2 = 16 MB
  int* counts = (int*)(ws + 262144 + 16777216);     // 128 KB

  hipLaunchKernelGGL(prep_w3, dim3(64), dim3(256), 0, stream, W3, W3f);
  hipLaunchKernelGGL(embed_scatter, dim3(512), dim3(512), 0, stream,
                     dstart, dend, W1, b1, W2, b2, swz, counts);
  hipLaunchKernelGGL(layer3, dim3(256), dim3(256), 0, stream,
                     swz, counts, W3f, b3, out);
}

// Round 4
// 111.325 us; speedup vs baseline: 1.0790x; 1.0015x over previous
//
#include <hip/hip_runtime.h>
#include <hip/hip_bf16.h>

typedef _Float16 half8 __attribute__((ext_vector_type(8)));
typedef _Float16 half4v __attribute__((ext_vector_type(4)));
typedef float floatx4 __attribute__((ext_vector_type(4)));
typedef float float4v __attribute__((ext_vector_type(4)));

// 100^(i/8), i=0..7, correctly rounded
__device__ const float FREQS[8] = {
    1.0f, 1.7782794100389228f, 3.1622776601683795f, 5.623413251903491f,
    10.0f, 17.78279410038923f, 31.622776601683793f, 56.23413251903491f};

// sin/cos of m (radians) via 2-term Cody-Waite reduction into revolutions,
// then v_sin_f32/v_cos_f32. Error ~|m|*2^-48, far below f16 rounding.
__device__ inline void fsincos(float m, float& s, float& c) {
  constexpr double I2PI_D = 0.15915494309189533576888376337251;
  constexpr float HI = (float)I2PI_D;
  constexpr float LO = (float)(I2PI_D - (double)HI);
  float k = rintf(m * HI);
  float f = fmaf(m, HI, -k);
  f = fmaf(m, LO, f);
  s = __builtin_amdgcn_sinf(f);
  c = __builtin_amdgcn_cosf(f);
}

// fast silu: v_exp + v_rcp (~1ulp), avoids the precise-division sequence
__device__ inline float fsilu(float x) {
  return x * __builtin_amdgcn_rcpf(1.f + __expf(-x));
}

// ---------------- kernel 1: W3 prep + feats + L1 + L2 + one-hot MFMA scatter --------
// 512 blocks = (bv[6]|tsel[1]|pg[2]), 512 threads (8 waves), 256 pts as 2x128 chunks.
// Prologue absorbs W3->fragment-major prep (tid<32: one half8 frag each,
// 512*32 = 16384 frags exactly once; consumed only by the NEXT dispatch, so
// stream order guarantees visibility -- no grid sync needed).
// Wave w: L1 for its 16 pts/chunk (h1^T via swapped MFMA -> packed LDS), then
// L2 + scatter for 32 cols [32w,32w+32). Scatter via mfma_16x16x16f16 one-hot A
// materialized in LDS (oneh[cell][pt]) by the 128 point-owner threads; chunk-1
// uses incremental clear (each setter zeroes its previous slot).
#define HS 136
#define OHS 136
__global__ __launch_bounds__(512, 4) void embed_scatter(
    const float* __restrict__ dstart, const float* __restrict__ dend,
    const float* __restrict__ W1, const float* __restrict__ b1,
    const float* __restrict__ W2, const float* __restrict__ b2,
    const float* __restrict__ W3, _Float16* __restrict__ W3f,
    _Float16* __restrict__ swz, int* __restrict__ counts) {
  __shared__ __align__(16) _Float16 h1t[128 * HS];   // 34816 B
  __shared__ __align__(16) _Float16 oneh[64 * OHS];  // 17408 B one-hot [cell][pt]
  __shared__ __align__(16) _Float16 W1lds[4096];     // 8192 B
  __shared__ float b1lds[128];
  __shared__ int hist[64];

  int bid = blockIdx.x;
  int tid = threadIdx.x;
  int lane = tid & 63, w = tid >> 6, ln = lane & 15, q = lane >> 4;

  // ---- absorbed W3 prep: frag f = bid*32 + tid ----
  if (tid < 32) {
    int f = bid * 32 + tid;
    int fln = f & 15, fq = (f >> 4) & 3, fks = (f >> 6) & 7, fit = f >> 9;
    int n = fit * 16 + fln;
    half8 t;
    for (int j = 0; j < 8; j++)
      t[j] = (_Float16)W3[(size_t)(fks * 32 + fq * 8 + j) * 512 + n];
    *(half8*)&W3f[(size_t)f * 8] = t;
  }

  int bv = bid >> 3, tsel = (bid >> 2) & 1, pg = bid & 3;
  const float* src = tsel ? dend : dstart;

  // stage W1 (f32 [32][128] row-major) -> W1lds[n*32+k] f16, coalesced reads
  {
    float4v v0 = *(const float4v*)&W1[tid * 8];
    float4v v1 = *(const float4v*)&W1[tid * 8 + 4];
    for (int e = 0; e < 8; e++) {
      int idx = tid * 8 + e;
      int k = idx >> 7, n = idx & 127;
      W1lds[n * 32 + k] = (_Float16)(e < 4 ? v0[e] : v1[e - 4]);
    }
  }
  if (tid < 128) b1lds[tid] = b1[tid];
  if (tid < 64) hist[tid] = 0;
  {  // zero one-hot for chunk 0
    half8 zz = {};
    for (int i = tid; i < (64 * OHS) / 8; i += 512) ((half8*)oneh)[i] = zz;
  }

  // B-frag of W2 (f32 [128][256] row-major): n=32w+16nt+ln, k=32ks+8q+j
  half8 w2f[2][4];
  float b2v[2];
  for (int nt = 0; nt < 2; nt++) {
    int n = w * 32 + nt * 16 + ln;
    b2v[nt] = b2[n];
    for (int ks = 0; ks < 4; ks++) {
      half8 t;
      for (int j = 0; j < 8; j++)
        t[j] = (_Float16)W2[(size_t)(ks * 32 + q * 8 + j) * 256 + n];
      w2f[nt][ks] = t;
    }
  }
  floatx4 sacc[4][2];  // cell=16mc+4q+r, col=32w+16nt+ln
  for (int mc = 0; mc < 4; mc++)
    for (int nt = 0; nt < 2; nt++) sacc[mc][nt] = (floatx4){0.f, 0.f, 0.f, 0.f};

  float fA = FREQS[2 * q], fB = FREQS[2 * q + 1];
  int pbase = bv * 1024 + pg * 256;
  int prevcell = 0;
  __syncthreads();

  for (int c = 0; c < 2; c++) {
    int pl = c * 128 + w * 16 + ln;
    float2 xy = *(const float2*)&src[(size_t)(pbase + pl) * 2];
    if (q == 0) {
      int cell = ((int)xy.x >> 6) * 8 + ((int)xy.y >> 6);
      if (c) oneh[prevcell * OHS + w * 16 + ln] = (_Float16)0.0f;  // clear old
      prevcell = cell;
      atomicAdd(&hist[cell], 1);
      oneh[cell * OHS + w * 16 + ln] = (_Float16)1.0f;  // set new
    }
    half8 fb;  // feats B-frag: n=pt=ln, k=8q+j -> freqs 2q,2q+1
    {
      float s, cc2;
      fsincos(xy.x * fA, s, cc2); fb[0] = (_Float16)s; fb[2] = (_Float16)cc2;
      fsincos(xy.y * fA, s, cc2); fb[1] = (_Float16)s; fb[3] = (_Float16)cc2;
      fsincos(xy.x * fB, s, cc2); fb[4] = (_Float16)s; fb[6] = (_Float16)cc2;
      fsincos(xy.y * fB, s, cc2); fb[5] = (_Float16)s; fb[7] = (_Float16)cc2;
    }
    // L1 swapped: C[m=h1col][n=pt]; silu -> packed b64 LDS write
#pragma unroll 2
    for (int mtW = 0; mtW < 8; mtW++) {
      half8 w1f = *(const half8*)&W1lds[(mtW * 16 + ln) * 32 + q * 8];
      floatx4 c1 = *(const floatx4*)&b1lds[mtW * 16 + q * 4];
      c1 = __builtin_amdgcn_mfma_f32_16x16x32_f16(w1f, fb, c1, 0, 0, 0);
      half4v hv;
      for (int r = 0; r < 4; r++) hv[r] = (_Float16)fsilu(c1[r]);
      *(half4v*)&h1t[(w * 16 + ln) * HS + mtW * 16 + q * 4] = hv;
    }
    __syncthreads();
    // L2 + one-hot scatter; unroll 1 keeps peak VGPR demand < 128 (no spills)
#pragma unroll 1
    for (int mt = 0; mt < 8; mt++) {
      half8 af[4];
      for (int ks = 0; ks < 4; ks++)
        af[ks] = *(const half8*)&h1t[(mt * 16 + ln) * HS + ks * 32 + q * 8];
      floatx4 cc0 = {b2v[0], b2v[0], b2v[0], b2v[0]};
      floatx4 cc1 = {b2v[1], b2v[1], b2v[1], b2v[1]};
      for (int ks = 0; ks < 4; ks++) {
        cc0 = __builtin_amdgcn_mfma_f32_16x16x32_f16(af[ks], w2f[0][ks], cc0, 0, 0, 0);
        cc1 = __builtin_amdgcn_mfma_f32_16x16x32_f16(af[ks], w2f[1][ks], cc1, 0, 0, 0);
      }
      half4v hb0, hb1;  // C-layout == scatter B-layout (k=pt=4q+r, n=col=ln)
      for (int r = 0; r < 4; r++) {
        hb0[r] = (_Float16)fsilu(cc0[r]);
        hb1[r] = (_Float16)fsilu(cc1[r]);
      }
      for (int mc = 0; mc < 4; mc++) {
        // one-hot A-frag: m=16mc+ln (cell), k=4q+j (pt) -- conflict-free b64
        half4v ao = *(const half4v*)&oneh[(mc * 16 + ln) * OHS + mt * 16 + q * 4];
        sacc[mc][0] = __builtin_amdgcn_mfma_f32_16x16x16f16(ao, hb0, sacc[mc][0], 0, 0, 0);
        sacc[mc][1] = __builtin_amdgcn_mfma_f32_16x16x16f16(ao, hb1, sacc[mc][1], 0, 0, 0);
      }
    }
    __syncthreads();
  }
  // coalesced swizzled store: element (bid, mc, wnt=2w+nt, lane) = half4 (r0..r3)
  for (int mc = 0; mc < 4; mc++)
    for (int nt = 0; nt < 2; nt++) {
      half4v hv;
      for (int r = 0; r < 4; r++) hv[r] = (_Float16)sacc[mc][nt][r];
      *(half4v*)&swz[((((size_t)bid * 4 + mc) * 16 + w * 2 + nt) * 64 + lane) * 4] = hv;
    }
  if (tid < 64) counts[bid * 64 + tid] = hist[tid];
}

// ---------------- kernel 2: out = (Σ_pg partial) @ W3 + count*b3 ----------------
// 256 blocks = (bvts[128], ocol-half[2]): each block owns ALL 64 cells and 256
// output cols. Unswizzles 4 pg partials into a 64x256 f16 LDS tile (full K),
// then swapped GEMM (A=W3 frags m=ocol, B=cells n=ln within 4 cell-tiles).
// i-outer / ct-inner: each W3f fragment is fetched exactly once per block.
#define AS 264
__global__ __launch_bounds__(256) void layer3(
    const _Float16* __restrict__ swz, const int* __restrict__ counts,
    const _Float16* __restrict__ W3f, const float* __restrict__ b3,
    float* __restrict__ out) {
  __shared__ _Float16 a_lds[64 * AS];  // 33792 B
  __shared__ float cnt_s[64];
  int bb = blockIdx.x;
  int bvts = bb >> 1, oh = bb & 1;
  int tid = threadIdx.x;
  // unswizzle + 4-pg reduce: f in 0..4095 indexes (mc,wnt,lane) half4v groups
  for (int it = 0; it < 16; it++) {
    int f = it * 256 + tid;
    size_t base = ((size_t)bvts * 4) * 4096 + f;
    half4v s = (*(const half4v*)&swz[base * 4] +
                *(const half4v*)&swz[(base + 4096) * 4]) +
               (*(const half4v*)&swz[(base + 8192) * 4] +
                *(const half4v*)&swz[(base + 12288) * 4]);
    int mc = f >> 10, wnt = (f >> 6) & 15, lane2 = f & 63;
    int q2 = lane2 >> 4, ln2 = lane2 & 15;
    int k = wnt * 16 + ln2;
    for (int r = 0; r < 4; r++) a_lds[(mc * 16 + q2 * 4 + r) * AS + k] = s[r];
  }
  if (tid < 64) {
    int base = bvts * 4 * 64 + tid;
    cnt_s[tid] = (float)(counts[base] + counts[base + 64] +
                         counts[base + 128] + counts[base + 192]);
  }
  __syncthreads();
  int lane = tid & 63, w = tid >> 6, ln = lane & 15, q = lane >> 4;
  for (int ii = 0; ii < 4; ii++) {
    int ig = oh * 16 + w * 4 + ii;  // 16-col tile of 512
    half8 wf[8];
    for (int ks = 0; ks < 8; ks++)
      wf[ks] = *(const half8*)&W3f[((size_t)(ig * 8 + ks) * 64 + lane) * 8];
    floatx4 b3v = *(const floatx4*)&b3[ig * 16 + q * 4];
    for (int ct = 0; ct < 4; ct++) {
      half8 af[8];  // B-frag: n=cell=ct*16+ln, k=32ks+8q+j
      for (int ks = 0; ks < 8; ks++)
        af[ks] = *(const half8*)&a_lds[(ct * 16 + ln) * AS + ks * 32 + q * 8];
      floatx4 acc = {0.f, 0.f, 0.f, 0.f};
      for (int ks = 0; ks < 8; ks++)
        acc = __builtin_amdgcn_mfma_f32_16x16x32_f16(wf[ks], af[ks], acc, 0, 0, 0);
      float cntf = cnt_s[ct * 16 + ln];
      for (int r = 0; r < 4; r++)
        out[((size_t)bvts * 512 + ig * 16 + q * 4 + r) * 64 + ct * 16 + ln] =
            acc[r] + cntf * b3v[r];
    }
  }
}

extern "C" void kernel_launch(void* const* d_in, const int* in_sizes, int n_in,
                              void* d_out, int out_size, void* d_ws, size_t ws_size,
                              hipStream_t stream) {
  const float* dstart = (const float*)d_in[0];
  const float* dend = (const float*)d_in[1];
  const float* W1 = (const float*)d_in[2];
  const float* b1 = (const float*)d_in[3];
  const float* W2 = (const float*)d_in[4];
  const float* b2 = (const float*)d_in[5];
  const float* W3 = (const float*)d_in[6];
  const float* b3 = (const float*)d_in[7];
  float* out = (float*)d_out;

  char* ws = (char*)d_ws;
  _Float16* W3f = (_Float16*)(ws);                  // 512*256*2 = 256 KB
  _Float16* swz = (_Float16*)(ws + 262144);         // 512*64*256*2 = 16 MB
  int* counts = (int*)(ws + 262144 + 16777216);     // 128 KB

  hipLaunchKernelGGL(embed_scatter, dim3(512), dim3(512), 0, stream,
                     dstart, dend, W1, b1, W2, b2, W3, W3f, swz, counts);
  hipLaunchKernelGGL(layer3, dim3(256), dim3(256), 0, stream,
                     swz, counts, W3f, b3, out);
}

// Round 5
// 109.873 us; speedup vs baseline: 1.0932x; 1.0132x over previous
//
#include <hip/hip_runtime.h>
#include <hip/hip_bf16.h>

typedef _Float16 half8 __attribute__((ext_vector_type(8)));
typedef _Float16 half4v __attribute__((ext_vector_type(4)));
typedef float floatx4 __attribute__((ext_vector_type(4)));
typedef float float4v __attribute__((ext_vector_type(4)));

// 100^(i/8), i=0..7, correctly rounded
__device__ const float FREQS[8] = {
    1.0f, 1.7782794100389228f, 3.1622776601683795f, 5.623413251903491f,
    10.0f, 17.78279410038923f, 31.622776601683793f, 56.23413251903491f};

// sin/cos of m (radians) via 2-term Cody-Waite reduction into revolutions,
// then v_sin_f32/v_cos_f32. Error ~|m|*2^-48, far below f16 rounding.
__device__ inline void fsincos(float m, float& s, float& c) {
  constexpr double I2PI_D = 0.15915494309189533576888376337251;
  constexpr float HI = (float)I2PI_D;
  constexpr float LO = (float)(I2PI_D - (double)HI);
  float k = rintf(m * HI);
  float f = fmaf(m, HI, -k);
  f = fmaf(m, LO, f);
  s = __builtin_amdgcn_sinf(f);
  c = __builtin_amdgcn_cosf(f);
}

// paired silu: ONE v_rcp for two sigmoids via 1/(a0*a1). e clamped to 1e18 so
// the product can't overflow f32 (clamped branch still gives silu ~= 0 exactly
// like the unpaired inf->rcp->0 path). rel err ~2ulp f32, far below f16 rounding.
__device__ inline void fsilu2(float x0, float x1, float& y0, float& y1) {
  float e0 = fminf(__expf(-x0), 1e18f);
  float e1 = fminf(__expf(-x1), 1e18f);
  float a0 = 1.f + e0, a1 = 1.f + e1;
  float r = __builtin_amdgcn_rcpf(a0 * a1);
  y0 = x0 * (a1 * r);
  y1 = x1 * (a0 * r);
}

// ---------------- kernel 1: W3 prep + feats + L1 + L2 + one-hot MFMA scatter --------
// 512 blocks = (bv[6]|tsel[1]|pg[2]), 512 threads (8 waves), 256 pts as 2x128 chunks.
// Prologue absorbs W3->fragment-major prep (tid<32: one half8 frag each,
// 512*32 = 16384 frags exactly once; consumed only by the NEXT dispatch, so
// stream order guarantees visibility -- no grid sync needed).
// Wave w: L1 for its 16 pts/chunk (h1^T via swapped MFMA -> packed LDS), then
// L2 + scatter for 32 cols [32w,32w+32). Scatter via mfma_16x16x16f16 one-hot A
// materialized in LDS (oneh[cell][pt]) by the 128 point-owner threads; chunk-1
// uses incremental clear (each setter zeroes its previous slot).
#define HS 136
#define OHS 136
__global__ __launch_bounds__(512, 4) void embed_scatter(
    const float* __restrict__ dstart, const float* __restrict__ dend,
    const float* __restrict__ W1, const float* __restrict__ b1,
    const float* __restrict__ W2, const float* __restrict__ b2,
    const float* __restrict__ W3, _Float16* __restrict__ W3f,
    _Float16* __restrict__ swz, int* __restrict__ counts) {
  __shared__ __align__(16) _Float16 h1t[128 * HS];   // 34816 B
  __shared__ __align__(16) _Float16 oneh[64 * OHS];  // 17408 B one-hot [cell][pt]
  __shared__ __align__(16) _Float16 W1lds[4096];     // 8192 B
  __shared__ float b1lds[128];
  __shared__ int hist[64];

  int bid = blockIdx.x;
  int tid = threadIdx.x;
  int lane = tid & 63, w = tid >> 6, ln = lane & 15, q = lane >> 4;

  // ---- absorbed W3 prep: frag f = bid*32 + tid ----
  if (tid < 32) {
    int f = bid * 32 + tid;
    int fln = f & 15, fq = (f >> 4) & 3, fks = (f >> 6) & 7, fit = f >> 9;
    int n = fit * 16 + fln;
    half8 t;
    for (int j = 0; j < 8; j++)
      t[j] = (_Float16)W3[(size_t)(fks * 32 + fq * 8 + j) * 512 + n];
    *(half8*)&W3f[(size_t)f * 8] = t;
  }

  int bv = bid >> 3, tsel = (bid >> 2) & 1, pg = bid & 3;
  const float* src = tsel ? dend : dstart;

  // stage W1 (f32 [32][128] row-major) -> W1lds[n*32+k] f16, coalesced reads
  {
    float4v v0 = *(const float4v*)&W1[tid * 8];
    float4v v1 = *(const float4v*)&W1[tid * 8 + 4];
    for (int e = 0; e < 8; e++) {
      int idx = tid * 8 + e;
      int k = idx >> 7, n = idx & 127;
      W1lds[n * 32 + k] = (_Float16)(e < 4 ? v0[e] : v1[e - 4]);
    }
  }
  if (tid < 128) b1lds[tid] = b1[tid];
  if (tid < 64) hist[tid] = 0;
  {  // zero one-hot for chunk 0
    half8 zz = {};
    for (int i = tid; i < (64 * OHS) / 8; i += 512) ((half8*)oneh)[i] = zz;
  }

  // B-frag of W2 (f32 [128][256] row-major): n=32w+16nt+ln, k=32ks+8q+j
  half8 w2f[2][4];
  float b2v[2];
  for (int nt = 0; nt < 2; nt++) {
    int n = w * 32 + nt * 16 + ln;
    b2v[nt] = b2[n];
    for (int ks = 0; ks < 4; ks++) {
      half8 t;
      for (int j = 0; j < 8; j++)
        t[j] = (_Float16)W2[(size_t)(ks * 32 + q * 8 + j) * 256 + n];
      w2f[nt][ks] = t;
    }
  }
  floatx4 sacc[4][2];  // cell=16mc+4q+r, col=32w+16nt+ln
  for (int mc = 0; mc < 4; mc++)
    for (int nt = 0; nt < 2; nt++) sacc[mc][nt] = (floatx4){0.f, 0.f, 0.f, 0.f};

  float fA = FREQS[2 * q], fB = FREQS[2 * q + 1];
  int pbase = bv * 1024 + pg * 256;
  int prevcell = 0;
  __syncthreads();

  for (int c = 0; c < 2; c++) {
    int pl = c * 128 + w * 16 + ln;
    float2 xy = *(const float2*)&src[(size_t)(pbase + pl) * 2];
    if (q == 0) {
      int cell = ((int)xy.x >> 6) * 8 + ((int)xy.y >> 6);
      if (c) oneh[prevcell * OHS + w * 16 + ln] = (_Float16)0.0f;  // clear old
      prevcell = cell;
      atomicAdd(&hist[cell], 1);
      oneh[cell * OHS + w * 16 + ln] = (_Float16)1.0f;  // set new
    }
    half8 fb;  // feats B-frag: n=pt=ln, k=8q+j -> freqs 2q,2q+1
    {
      float s, cc2;
      fsincos(xy.x * fA, s, cc2); fb[0] = (_Float16)s; fb[2] = (_Float16)cc2;
      fsincos(xy.y * fA, s, cc2); fb[1] = (_Float16)s; fb[3] = (_Float16)cc2;
      fsincos(xy.x * fB, s, cc2); fb[4] = (_Float16)s; fb[6] = (_Float16)cc2;
      fsincos(xy.y * fB, s, cc2); fb[5] = (_Float16)s; fb[7] = (_Float16)cc2;
    }
    // L1 swapped: C[m=h1col][n=pt]; silu -> packed b64 LDS write
#pragma unroll 2
    for (int mtW = 0; mtW < 8; mtW++) {
      half8 w1f = *(const half8*)&W1lds[(mtW * 16 + ln) * 32 + q * 8];
      floatx4 c1 = *(const floatx4*)&b1lds[mtW * 16 + q * 4];
      c1 = __builtin_amdgcn_mfma_f32_16x16x32_f16(w1f, fb, c1, 0, 0, 0);
      float y0, y1, y2, y3;
      fsilu2(c1[0], c1[1], y0, y1);
      fsilu2(c1[2], c1[3], y2, y3);
      half4v hv;
      hv[0] = (_Float16)y0; hv[1] = (_Float16)y1;
      hv[2] = (_Float16)y2; hv[3] = (_Float16)y3;
      *(half4v*)&h1t[(w * 16 + ln) * HS + mtW * 16 + q * 4] = hv;
    }
    __syncthreads();
    // L2 + one-hot scatter; unroll 1 keeps peak VGPR demand < 128 (no spills)
#pragma unroll 1
    for (int mt = 0; mt < 8; mt++) {
      half8 af[4];
      for (int ks = 0; ks < 4; ks++)
        af[ks] = *(const half8*)&h1t[(mt * 16 + ln) * HS + ks * 32 + q * 8];
      floatx4 cc0 = {b2v[0], b2v[0], b2v[0], b2v[0]};
      floatx4 cc1 = {b2v[1], b2v[1], b2v[1], b2v[1]};
      for (int ks = 0; ks < 4; ks++) {
        cc0 = __builtin_amdgcn_mfma_f32_16x16x32_f16(af[ks], w2f[0][ks], cc0, 0, 0, 0);
        cc1 = __builtin_amdgcn_mfma_f32_16x16x32_f16(af[ks], w2f[1][ks], cc1, 0, 0, 0);
      }
      half4v hb0, hb1;  // C-layout == scatter B-layout (k=pt=4q+r, n=col=ln)
      {
        float z0, z1, z2, z3;
        fsilu2(cc0[0], cc0[1], z0, z1);
        fsilu2(cc0[2], cc0[3], z2, z3);
        hb0[0] = (_Float16)z0; hb0[1] = (_Float16)z1;
        hb0[2] = (_Float16)z2; hb0[3] = (_Float16)z3;
        fsilu2(cc1[0], cc1[1], z0, z1);
        fsilu2(cc1[2], cc1[3], z2, z3);
        hb1[0] = (_Float16)z0; hb1[1] = (_Float16)z1;
        hb1[2] = (_Float16)z2; hb1[3] = (_Float16)z3;
      }
      for (int mc = 0; mc < 4; mc++) {
        // one-hot A-frag: m=16mc+ln (cell), k=4q+j (pt) -- conflict-free b64
        half4v ao = *(const half4v*)&oneh[(mc * 16 + ln) * OHS + mt * 16 + q * 4];
        sacc[mc][0] = __builtin_amdgcn_mfma_f32_16x16x16f16(ao, hb0, sacc[mc][0], 0, 0, 0);
        sacc[mc][1] = __builtin_amdgcn_mfma_f32_16x16x16f16(ao, hb1, sacc[mc][1], 0, 0, 0);
      }
    }
    __syncthreads();
  }
  // coalesced swizzled store: element (bid, mc, wnt=2w+nt, lane) = half4 (r0..r3)
  for (int mc = 0; mc < 4; mc++)
    for (int nt = 0; nt < 2; nt++) {
      half4v hv;
      for (int r = 0; r < 4; r++) hv[r] = (_Float16)sacc[mc][nt][r];
      *(half4v*)&swz[((((size_t)bid * 4 + mc) * 16 + w * 2 + nt) * 64 + lane) * 4] = hv;
    }
  if (tid < 64) counts[bid * 64 + tid] = hist[tid];
}

// ---------------- kernel 2: out = (Σ_pg partial) @ W3 + count*b3 ----------------
// 256 blocks = (bvts[128], ocol-half[2]) x 512 threads (8 waves -> 2 waves/SIMD,
// double the TLP of the prior 256-thread version: unswizzle L2 latency now has
// a second wave to hide behind). Unswizzles 4 pg partials into a 64x256 f16 LDS
// tile (full K), then swapped GEMM (A=W3 frags m=ocol, B=cells), 2 ig-tiles/wave.
// Traffic identical to prior round (swz 32MB, W3f 32MB, out 16.7MB).
#define AS 264
__global__ __launch_bounds__(512) void layer3(
    const _Float16* __restrict__ swz, const int* __restrict__ counts,
    const _Float16* __restrict__ W3f, const float* __restrict__ b3,
    float* __restrict__ out) {
  __shared__ _Float16 a_lds[64 * AS];  // 33792 B
  __shared__ float cnt_s[64];
  int bb = blockIdx.x;
  int bvts = bb >> 1, oh = bb & 1;
  int tid = threadIdx.x;
  // unswizzle + 4-pg reduce: f in 0..4095 indexes (mc,wnt,lane) half4v groups
  for (int it = 0; it < 8; it++) {
    int f = it * 512 + tid;
    size_t base = ((size_t)bvts * 4) * 4096 + f;
    half4v s = (*(const half4v*)&swz[base * 4] +
                *(const half4v*)&swz[(base + 4096) * 4]) +
               (*(const half4v*)&swz[(base + 8192) * 4] +
                *(const half4v*)&swz[(base + 12288) * 4]);
    int mc = f >> 10, wnt = (f >> 6) & 15, lane2 = f & 63;
    int q2 = lane2 >> 4, ln2 = lane2 & 15;
    int k = wnt * 16 + ln2;
    for (int r = 0; r < 4; r++) a_lds[(mc * 16 + q2 * 4 + r) * AS + k] = s[r];
  }
  if (tid < 64) {
    int base = bvts * 4 * 64 + tid;
    cnt_s[tid] = (float)(counts[base] + counts[base + 64] +
                         counts[base + 128] + counts[base + 192]);
  }
  __syncthreads();
  int lane = tid & 63, w = tid >> 6, ln = lane & 15, q = lane >> 4;
  for (int ii = 0; ii < 2; ii++) {
    int ig = oh * 16 + w * 2 + ii;  // 16-col tile of 512
    half8 wf[8];
    for (int ks = 0; ks < 8; ks++)
      wf[ks] = *(const half8*)&W3f[((size_t)(ig * 8 + ks) * 64 + lane) * 8];
    floatx4 b3v = *(const floatx4*)&b3[ig * 16 + q * 4];
    for (int ct = 0; ct < 4; ct++) {
      half8 af[8];  // B-frag: n=cell=ct*16+ln, k=32ks+8q+j
      for (int ks = 0; ks < 8; ks++)
        af[ks] = *(const half8*)&a_lds[(ct * 16 + ln) * AS + ks * 32 + q * 8];
      floatx4 acc = {0.f, 0.f, 0.f, 0.f};
      for (int ks = 0; ks < 8; ks++)
        acc = __builtin_amdgcn_mfma_f32_16x16x32_f16(wf[ks], af[ks], acc, 0, 0, 0);
      float cntf = cnt_s[ct * 16 + ln];
      for (int r = 0; r < 4; r++)
        out[((size_t)bvts * 512 + ig * 16 + q * 4 + r) * 64 + ct * 16 + ln] =
            acc[r] + cntf * b3v[r];
    }
  }
}

extern "C" void kernel_launch(void* const* d_in, const int* in_sizes, int n_in,
                              void* d_out, int out_size, void* d_ws, size_t ws_size,
                              hipStream_t stream) {
  const float* dstart = (const float*)d_in[0];
  const float* dend = (const float*)d_in[1];
  const float* W1 = (const float*)d_in[2];
  const float* b1 = (const float*)d_in[3];
  const float* W2 = (const float*)d_in[4];
  const float* b2 = (const float*)d_in[5];
  const float* W3 = (const float*)d_in[6];
  const float* b3 = (const float*)d_in[7];
  float* out = (float*)d_out;

  char* ws = (char*)d_ws;
  _Float16* W3f = (_Float16*)(ws);                  // 512*256*2 = 256 KB
  _Float16* swz = (_Float16*)(ws + 262144);         // 512*64*256*2 = 16 MB
  int* counts = (int*)(ws + 262144 + 16777216);     // 128 KB

  hipLaunchKernelGGL(embed_scatter, dim3(512), dim3(512), 0, stream,
                     dstart, dend, W1, b1, W2, b2, W3, W3f, swz, counts);
  hipLaunchKernelGGL(layer3, dim3(256), dim3(512), 0, stream,
                     swz, counts, W3f, b3, out);
}